// Round 6
// baseline (204.592 us; speedup 1.0000x reference)
//
#include <hip/hip_runtime.h>

// HoloAttentionV2: prep -> G1: x@[Wk|Wv] (128^2-tile BK=64 m97-style dbuf GEMM,
// 2 blocks/CU; epilogue emits packed f16x2 phasor of 10*k + f16 v) -> scan_part
// -> scan_out -> G2: y@Wo (same GEMM, f32 out). 5 launches.
// B=2 T=4096 DM=1024 H=16 D=64, M=8192, K=1024 both GEMMs.

#define B_ 2
#define T_ 4096
#define H_ 16
#define D_ 64
#define M_ (B_*T_)
#define PHASE_SCALE 10.0f

typedef _Float16 f16;
typedef unsigned int u32;
typedef __attribute__((ext_vector_type(8))) _Float16 f16x8;
typedef __attribute__((ext_vector_type(4))) _Float16 f16x4;
typedef __attribute__((ext_vector_type(2))) _Float16 f16x2;
typedef __attribute__((ext_vector_type(4))) float f32x4;

union pk_u { u32 u; f16x2 v; };

// ---------------- prep: z<3 weight transpose-cvt, z==3 x cvt ----------------

__global__ void k_prep(const float* __restrict__ x, const float* __restrict__ Wk,
                       const float* __restrict__ Wv, const float* __restrict__ Wo,
                       f16* __restrict__ xh, f16* __restrict__ Wkvt, f16* __restrict__ Wot) {
  __shared__ float tile[32][33];
  const int z = blockIdx.z;
  const int tx = threadIdx.x, ty = threadIdx.y;
  if (z == 3) {
    const int blk = blockIdx.y * 32 + blockIdx.x;
    const size_t base = (size_t)blk * 256 + ty * 32 + tx;
    #pragma unroll
    for (int i = 0; i < 8; ++i) {
      size_t idx = (base + (size_t)i * 262144) * 4;
      float4 v = *reinterpret_cast<const float4*>(x + idx);
      f16x4 o; o[0] = (f16)v.x; o[1] = (f16)v.y; o[2] = (f16)v.z; o[3] = (f16)v.w;
      *reinterpret_cast<f16x4*>(xh + idx) = o;
    }
    return;
  }
  const float* src = (z == 0) ? Wk : (z == 1) ? Wv : Wo;
  f16* dst = (z == 0) ? Wkvt : (z == 1) ? (Wkvt + (size_t)1024 * 1024) : Wot;
  const int bx = blockIdx.x, by = blockIdx.y;
  #pragma unroll
  for (int r = 0; r < 32; r += 8)
    tile[ty + r][tx] = src[(size_t)(by * 32 + ty + r) * 1024 + bx * 32 + tx];
  __syncthreads();
  #pragma unroll
  for (int r = 0; r < 32; r += 8)
    dst[(size_t)(bx * 32 + ty + r) * 1024 + by * 32 + tx] = (f16)tile[tx][ty + r];
}

// ---------------- 128x128-tile BK=64 GEMM, m97-style, 2 blocks/CU ------------
// A: M x 1024 f16. Bt: N x 1024 f16 (B^T). K=1024 -> 16 K-tiles.
// 256 thr = 4 waves (wr=wid>>1, wc=wid&1); wave tile 64x64 = 4x4 frags.
// LDS 64KiB dynamic: [A buf0 16K][A buf1 16K][B buf0 16K][B buf1 16K].
// XOR-swizzle (chunk ^= row&7) via pre-swizzled global src; linear LDS dest.
// Loop: STAGE(buf^1, kt+1) -> ds_read(buf) -> MFMA(setprio) -> __syncthreads()
// (compiler emits vmcnt(0)+lgkmcnt(0) drain at the barrier; hidden by the
//  co-resident second block -- the m97 TLP mechanism).
// MODE 1 (G1): col<1024 -> kcs u32 packed (cos,sin)(10*acc) f16x2; else vh f16.
// MODE 0 (G2): C f32, N=1024.
// Grid XCD-bijective swizzle (nwg%8==0 for 1024/512).

__device__ __forceinline__ void gl2lds16(const f16* g, char* l) {
  __builtin_amdgcn_global_load_lds((const __attribute__((address_space(1))) u32*)g,
                                   (__attribute__((address_space(3))) u32*)l, 16, 0, 0);
}

#define STAGE128(gp, ldsbase, kkt) do { \
  _Pragma("unroll") for (int i_ = 0; i_ < 4; ++i_) \
    gl2lds16((gp) + (size_t)(i_ * 32) * 1024 + (size_t)(kkt) * 64, \
             (ldsbase) + i_ * 4096 + tid * 16); \
} while (0)

template<int MODE>
__launch_bounds__(256, 2)
__global__ void k_gemm128(const f16* __restrict__ A, const f16* __restrict__ Bt,
                          u32* __restrict__ kcs, f16* __restrict__ vh,
                          float* __restrict__ o32) {
  extern __shared__ char smem[];
  char* sA = smem;
  char* sB = smem + 32768;

  const int tid  = threadIdx.x;
  const int lane = tid & 63;
  const int wid  = tid >> 6;
  const int wr   = wid >> 1, wc = wid & 1;
  const int lr   = lane & 15, hi = lane >> 4;

  // XCD-bijective block swizzle (nwg = 1024 or 512, both %8==0)
  const u32 lin = blockIdx.x + gridDim.x * blockIdx.y;
  const u32 nwg = gridDim.x * gridDim.y;
  const u32 q   = nwg >> 3;
  const u32 swz = (lin & 7) * q + (lin >> 3);
  const int m0  = (int)(swz & 63) * 128;
  const int n0  = (int)(swz >> 6) * 128;

  const int rsub = tid >> 3;                       // 0..31
  const int cswe = ((tid & 7) ^ (rsub & 7)) * 8;   // pre-swizzled elem offset
  const f16* gA = A  + (size_t)(m0 + rsub) * 1024 + cswe;
  const f16* gB = Bt + (size_t)(n0 + rsub) * 1024 + cswe;

  int offA[4][2], offB[4][2];
  #pragma unroll
  for (int mi = 0; mi < 4; ++mi)
    #pragma unroll
    for (int kk = 0; kk < 2; ++kk) {
      int ra = wr * 64 + mi * 16 + lr;
      offA[mi][kk] = ra * 128 + (((kk * 4 + hi) ^ (ra & 7)) << 4);
      int rb = wc * 64 + mi * 16 + lr;
      offB[mi][kk] = rb * 128 + (((kk * 4 + hi) ^ (rb & 7)) << 4);
    }

  f32x4 acc[4][4] = {};
  f16x8 aF[4][2], bF[4][2];

  STAGE128(gA, sA, 0);
  STAGE128(gB, sB, 0);
  __syncthreads();

  int cur = 0;
  for (int kt = 0; kt < 16; ++kt) {
    if (kt < 15) {
      STAGE128(gA, sA + (cur ^ 1) * 16384, kt + 1);
      STAGE128(gB, sB + (cur ^ 1) * 16384, kt + 1);
    }
    #pragma unroll
    for (int mi = 0; mi < 4; ++mi)
      #pragma unroll
      for (int kk = 0; kk < 2; ++kk) {
        aF[mi][kk] = *(const f16x8*)(sA + cur * 16384 + offA[mi][kk]);
        bF[mi][kk] = *(const f16x8*)(sB + cur * 16384 + offB[mi][kk]);
      }
    __builtin_amdgcn_s_setprio(1);
    #pragma unroll
    for (int mi = 0; mi < 4; ++mi)
      #pragma unroll
      for (int nj = 0; nj < 4; ++nj)
        #pragma unroll
        for (int kk = 0; kk < 2; ++kk)
          acc[mi][nj] = __builtin_amdgcn_mfma_f32_16x16x32_f16(
              aF[mi][kk], bF[nj][kk], acc[mi][nj], 0, 0, 0);
    __builtin_amdgcn_s_setprio(0);
    __syncthreads();   // vmcnt(0)+lgkmcnt(0)+barrier: next tile staged & reads done
    cur ^= 1;
  }

  // epilogue: C/D layout col=lane&15, row=(lane>>4)*4+reg (m89-verified)
  const int rb4 = hi * 4;
  #pragma unroll
  for (int mi = 0; mi < 4; ++mi) {
    const int row = m0 + wr * 64 + mi * 16 + rb4;
    #pragma unroll
    for (int nj = 0; nj < 4; ++nj) {
      const int col = n0 + wc * 64 + nj * 16 + lr;
      f32x4 a4 = acc[mi][nj];
      if (MODE == 1) {
        if (col < 1024) {
          #pragma unroll
          for (int r = 0; r < 4; ++r) {
            float s, c; __sincosf(PHASE_SCALE * a4[r], &s, &c);
            pk_u p; p.v[0] = (f16)c; p.v[1] = (f16)s;
            kcs[(size_t)(row + r) * 1024 + col] = p.u;
          }
        } else {
          #pragma unroll
          for (int r = 0; r < 4; ++r)
            vh[(size_t)(row + r) * 1024 + (col - 1024)] = (f16)a4[r];
        }
      } else {
        #pragma unroll
        for (int r = 0; r < 4; ++r)
          o32[(size_t)(row + r) * 1024 + col] = a4[r];
      }
    }
  }
}

// ---------------- scan: 64 chunks x 64 t; lane = d, wave = chunk -------------
// kcs: (M,1024) u32 packed f16x2 (cos,sin)(10*k). vh: (M,1024) f16 v.
// tot: [c][b][h][d] float4 {pos_re, pos_im, assoc_re, assoc_im}, c in [0,64)

__global__ void k_scan_part(const u32* __restrict__ kcs, const f16* __restrict__ vh,
                            const float* __restrict__ freqs, float4* __restrict__ tot) {
  const int bid = blockIdx.x;
  const int cg = bid & 15;
  const int h  = (bid >> 4) & 15;
  const int b  = bid >> 8;
  const int w  = threadIdx.x >> 6;
  const int d  = threadIdx.x & 63;
  const int c  = cg * 4 + w;
  const int t0 = c * 64;
  const int col = h * 64 + d;
  const float f = freqs[col];

  float bc = 0.f, bs = 0.f;              // binder = conj(k[t-1]) -> (bc,-bs)
  if (t0 > 0) {
    pk_u p; p.u = kcs[(size_t)(b * T_ + t0 - 1) * 1024 + col];
    bc = (float)p.v[0]; bs = (float)p.v[1];
  }
  double rev = (double)t0 * (double)f * 0.15915494309189535;  // f64 anchor
  rev -= floor(rev);
  float ph = (float)rev * 6.28318530717958647692f;
  float ri, rc; __sincosf(ph, &ri, &rc);
  float sf, cf; __sincosf(f, &sf, &cf);

  float pr = 0.f, pi = 0.f, ar = 0.f, ai = 0.f;
  #pragma unroll 8
  for (int tt = 0; tt < 64; ++tt) {
    size_t row = (size_t)(b * T_ + t0 + tt) * 1024 + col;
    float v = (float)vh[row];
    pk_u p; p.u = kcs[row];
    pr = fmaf(v, rc, pr); pi = fmaf(v, ri, pi);
    ar = fmaf(v, bc, ar); ai = fmaf(-v, bs, ai);
    bc = (float)p.v[0]; bs = (float)p.v[1];     // k_t phasor -> binder for t+1
    float nrc = rc * cf - ri * sf;
    ri = rc * sf + ri * cf; rc = nrc;
  }
  tot[((size_t)(c * 2 + b) * 16 + h) * 64 + d] = make_float4(pr, pi, ar, ai);
}

__global__ void k_scan_out(const u32* __restrict__ kcs, const f16* __restrict__ vh,
                           const float* __restrict__ freqs, const float4* __restrict__ tot,
                           const float* __restrict__ gate, f16* __restrict__ y) {
  const int bid = blockIdx.x;
  const int cg = bid & 15;
  const int h  = (bid >> 4) & 15;
  const int b  = bid >> 8;
  const int w  = threadIdx.x >> 6;
  const int d  = threadIdx.x & 63;
  const int c  = cg * 4 + w;
  const int t0 = c * 64;
  const int col = h * 64 + d;
  const float f = freqs[col];
  const float gp = gate[2 * h], ga = gate[2 * h + 1];

  float pr = 0.f, pi = 0.f, ar = 0.f, ai = 0.f;
  #pragma unroll 4
  for (int cc = 0; cc < c; ++cc) {
    float4 tv = tot[((size_t)(cc * 2 + b) * 16 + h) * 64 + d];
    pr += tv.x; pi += tv.y; ar += tv.z; ai += tv.w;
  }

  float bc = 0.f, bs = 0.f;
  if (t0 > 0) {
    pk_u p; p.u = kcs[(size_t)(b * T_ + t0 - 1) * 1024 + col];
    bc = (float)p.v[0]; bs = (float)p.v[1];
  }
  double rev = (double)t0 * (double)f * 0.15915494309189535;
  rev -= floor(rev);
  float ph = (float)rev * 6.28318530717958647692f;
  float ri, rc; __sincosf(ph, &ri, &rc);
  float sf, cf; __sincosf(f, &sf, &cf);

  #pragma unroll 8
  for (int tt = 0; tt < 64; ++tt) {
    int t = t0 + tt;
    size_t row = (size_t)(b * T_ + t) * 1024 + col;
    float v = (float)vh[row];
    pk_u p; p.u = kcs[row];
    pr = fmaf(v, rc, pr); pi = fmaf(v, ri, pi);     // cum_pos += v * rotor
    ar = fmaf(v, bc, ar); ai = fmaf(-v, bs, ai);    // cum_assoc += v * conj(k[t-1])
    float kc = (float)p.v[0], ks = (float)p.v[1];   // k_t phasor (probe)
    float inv = rsqrtf((float)(t + 1));
    float op = fmaf(pr, rc, pi * ri) * inv;         // Re(cum_pos * conj(rotor))
    float oa = fmaf(ar, kc, -(ai * ks)) * inv;      // Re(cum_assoc * k_t)
    y[row] = (f16)(gp * op + ga * oa);
    bc = kc; bs = ks;
    float nrc = rc * cf - ri * sf;
    ri = rc * sf + ri * cf; rc = nrc;
  }
}

// ---------------- launch ----------------

extern "C" void kernel_launch(void* const* d_in, const int* in_sizes, int n_in,
                              void* d_out, int out_size, void* d_ws, size_t ws_size,
                              hipStream_t stream) {
  const float* x     = (const float*)d_in[0];
  const float* Wk    = (const float*)d_in[1];
  const float* Wv    = (const float*)d_in[2];
  const float* Wo    = (const float*)d_in[3];
  const float* gate  = (const float*)d_in[4];
  const float* freqs = (const float*)d_in[5];
  float* out = (float*)d_out;

  char* ws = (char*)d_ws;
  size_t off = 0;
  auto alloc = [&](size_t bytes) { void* p = ws + off; off += (bytes + 255) & ~255ull; return p; };

  f16*    xh   = (f16*)   alloc((size_t)M_ * 1024 * sizeof(f16));   // aliased as y
  f16*    Wkvt = (f16*)   alloc((size_t)2048 * 1024 * sizeof(f16));
  f16*    Wot  = (f16*)   alloc((size_t)1024 * 1024 * sizeof(f16));
  u32*    kcs  = (u32*)   alloc((size_t)M_ * 1024 * sizeof(u32));
  f16*    vh   = (f16*)   alloc((size_t)M_ * 1024 * sizeof(f16));
  float4* tot  = (float4*)alloc((size_t)64 * B_ * H_ * D_ * sizeof(float4));
  f16*    yh   = xh;  // xh last read by GEMM1; scan_out writes y after

  hipFuncSetAttribute(reinterpret_cast<const void*>(&k_gemm128<1>),
                      hipFuncAttributeMaxDynamicSharedMemorySize, 65536);
  hipFuncSetAttribute(reinterpret_cast<const void*>(&k_gemm128<0>),
                      hipFuncAttributeMaxDynamicSharedMemorySize, 65536);

  hipLaunchKernelGGL(k_prep, dim3(32, 32, 4), dim3(32, 8), 0, stream,
                     x, Wk, Wv, Wo, xh, Wkvt, Wot);
  // G1: [k|v] = x @ [Wk|Wv]; cols<1024 -> phasor(10k) f16x2, cols>=1024 -> v f16
  hipLaunchKernelGGL(k_gemm128<1>, dim3(64, 16), dim3(256), 65536, stream,
                     xh, Wkvt, kcs, vh, nullptr);
  hipLaunchKernelGGL(k_scan_part, dim3(512), dim3(256), 0, stream, kcs, vh, freqs, tot);
  hipLaunchKernelGGL(k_scan_out,  dim3(512), dim3(256), 0, stream, kcs, vh, freqs, tot, gate, yh);
  // G2: out = y @ Wo (f32)
  hipLaunchKernelGGL(k_gemm128<0>, dim3(64, 8), dim3(256), 65536, stream,
                     yh, Wot, nullptr, nullptr, out);
}